// Round 1
// baseline (491.586 us; speedup 1.0000x reference)
//
#include <hip/hip_runtime.h>
#include <math.h>

#define DEV __device__ __forceinline__

DEV void wave_argmin(float& v, int& i) {
    #pragma unroll
    for (int off = 32; off; off >>= 1) {
        float ov = __shfl_xor(v, off, 64);
        int   oi = __shfl_xor(i, off, 64);
        if (ov < v || (ov == v && oi < i)) { v = ov; i = oi; }
    }
}

// ---------------- level 3: k=4, 64 src/graph, C=256, concat 128 -> out [4096,384]
__global__ __launch_bounds__(64) void knn3_kernel(
    const float* __restrict__ x, const float* __restrict__ pos_s,
    const float* __restrict__ pos_t, const float* __restrict__ x_skip,
    float* __restrict__ out)
{
    const int t = blockIdx.x, lane = threadIdx.x;
    const int g = t >> 8, sbase = g << 6;   // 256 tgts/graph, 64 srcs/graph
    const float qx = pos_t[t*3+0], qy = pos_t[t*3+1], qz = pos_t[t*3+2];
    const float qq = qx*qx + qy*qy + qz*qz;
    const int s = sbase + lane;
    const float px = pos_s[s*3+0], py = pos_s[s*3+1], pz = pos_s[s*3+2];
    const float pp = px*px + py*py + pz*pz;
    float myd = qq + pp - 2.f*(qx*px + qy*py + qz*pz);

    float w[4]; int row[4]; float wsum = 0.f;
    #pragma unroll
    for (int j = 0; j < 4; ++j) {
        float v = myd; int i = lane;
        wave_argmin(v, i);
        if (lane == i) myd = INFINITY;
        w[j] = 1.f / fmaxf(v, 1e-16f);
        row[j] = sbase + i;
        wsum += w[j];
    }
    const float inv = 1.f / wsum;
    #pragma unroll
    for (int cb = 0; cb < 4; ++cb) {
        const int c = lane + cb*64;
        float y = 0.f;
        #pragma unroll
        for (int j = 0; j < 4; ++j) y += w[j] * x[row[j]*256 + c];
        out[t*384 + c] = y * inv;
    }
    out[t*384 + 256 + lane]      = x_skip[t*128 + lane];
    out[t*384 + 256 + 64 + lane] = x_skip[t*128 + 64 + lane];
}

// ---------------- level 2: k=8, 256 src/graph, C=128, concat 64 -> out [16384,192]
__global__ __launch_bounds__(64) void knn2_kernel(
    const float* __restrict__ xsrc, const float* __restrict__ pos_s,
    const float* __restrict__ pos_t, const float* __restrict__ x_skip,
    float* __restrict__ out)
{
    const int t = blockIdx.x, lane = threadIdx.x;
    const int g = t >> 10, sbase = g << 8;  // 1024 tgts/graph, 256 srcs/graph
    const float qx = pos_t[t*3+0], qy = pos_t[t*3+1], qz = pos_t[t*3+2];
    const float qq = qx*qx + qy*qy + qz*qz;
    float d[4];
    #pragma unroll
    for (int m = 0; m < 4; ++m) {
        const int s = sbase + lane + m*64;
        const float px = pos_s[s*3+0], py = pos_s[s*3+1], pz = pos_s[s*3+2];
        d[m] = qq + px*px + py*py + pz*pz - 2.f*(qx*px + qy*py + qz*pz);
    }
    float w[8]; int row[8]; float wsum = 0.f;
    #pragma unroll
    for (int j = 0; j < 8; ++j) {
        float v = d[0]; int i = lane;   // strict < keeps lowest index on ties
        #pragma unroll
        for (int m = 1; m < 4; ++m)
            if (d[m] < v) { v = d[m]; i = lane + m*64; }
        wave_argmin(v, i);
        const int wl = i & 63, wm = i >> 6;
        if (lane == wl) {
            #pragma unroll
            for (int m = 0; m < 4; ++m) if (m == wm) d[m] = INFINITY;
        }
        w[j] = 1.f / fmaxf(v, 1e-16f);
        row[j] = sbase + i;
        wsum += w[j];
    }
    const float inv = 1.f / wsum;
    #pragma unroll
    for (int cb = 0; cb < 2; ++cb) {
        const int c = lane + cb*64;
        float y = 0.f;
        #pragma unroll
        for (int j = 0; j < 8; ++j) y += w[j] * xsrc[row[j]*128 + c];
        out[t*192 + c] = y * inv;
    }
    out[t*192 + 128 + lane] = x_skip[t*64 + lane];
}

// ---------------- level 1: k=16, 1024 src/graph, C=64, concat 3 -> out [65536,67]
__global__ __launch_bounds__(64) void knn1_kernel(
    const float* __restrict__ xsrc, const float* __restrict__ pos_s,
    const float* __restrict__ pos_t, const float* __restrict__ x_skip,
    float* __restrict__ out)
{
    __shared__ float d2s[1024];
    const int t = blockIdx.x, lane = threadIdx.x;
    const int g = t >> 12, sbase = g << 10; // 4096 tgts/graph, 1024 srcs/graph
    const float qx = pos_t[t*3+0], qy = pos_t[t*3+1], qz = pos_t[t*3+2];
    const float qq = qx*qx + qy*qy + qz*qz;
    #pragma unroll
    for (int m = 0; m < 16; ++m) {
        const int s = sbase + lane + m*64;
        const float px = pos_s[s*3+0], py = pos_s[s*3+1], pz = pos_s[s*3+2];
        d2s[lane + m*64] = qq + px*px + py*py + pz*pz - 2.f*(qx*px + qy*py + qz*pz);
    }
    __syncthreads();
    float w[16]; int row[16]; float wsum = 0.f;
    #pragma unroll
    for (int j = 0; j < 16; ++j) {
        float v = INFINITY; int i = 0x7fffffff;
        #pragma unroll
        for (int m = 0; m < 16; ++m) {
            const float dv = d2s[lane + m*64];
            const int di = lane + m*64;
            if (dv < v || (dv == v && di < i)) { v = dv; i = di; }
        }
        wave_argmin(v, i);
        if (lane == (i & 63)) d2s[i] = INFINITY;
        __syncthreads();
        w[j] = 1.f / fmaxf(v, 1e-16f);
        row[j] = sbase + i;
        wsum += w[j];
    }
    float y = 0.f;
    const float inv = 1.f / wsum;
    #pragma unroll
    for (int j = 0; j < 16; ++j) y += w[j] * xsrc[row[j]*64 + lane];
    out[t*67 + lane] = y * inv;
    if (lane < 3) out[t*67 + 64 + lane] = x_skip[t*3 + lane];
}

// ---------------- fused 2-layer MLP: out = (tanh(in*Wa^T+ba))*Wb^T+bb
// block = C1 threads, each block does ROWS rows.
template<int K1, int C1, int C2, int ROWS>
__global__ void mlp2_kernel(
    const float* __restrict__ in, const float* __restrict__ Wa,
    const float* __restrict__ ba, const float* __restrict__ Wb,
    const float* __restrict__ bb, float* __restrict__ out, int N)
{
    __shared__ float xt[ROWS * K1];
    __shared__ float h1[ROWS * C1];
    const int tid = threadIdx.x;
    const int row0 = blockIdx.x * ROWS;

    for (int f = tid; f < ROWS * K1; f += C1)
        xt[f] = in[row0 * K1 + f];
    __syncthreads();

    float acc[ROWS];
    #pragma unroll
    for (int r = 0; r < ROWS; ++r) acc[r] = ba[tid];
    for (int k = 0; k < K1; ++k) {
        const float wv = Wa[tid * K1 + k];
        #pragma unroll
        for (int r = 0; r < ROWS; ++r) acc[r] += xt[r * K1 + k] * wv;
    }
    #pragma unroll
    for (int r = 0; r < ROWS; ++r) h1[r * C1 + tid] = tanhf(acc[r]);
    __syncthreads();

    if (tid < C2) {
        float acc2[ROWS];
        #pragma unroll
        for (int r = 0; r < ROWS; ++r) acc2[r] = bb[tid];
        for (int k = 0; k < C1; ++k) {
            const float wv = Wb[tid * C1 + k];
            #pragma unroll
            for (int r = 0; r < ROWS; ++r) acc2[r] += h1[r * C1 + k] * wv;
        }
        #pragma unroll
        for (int r = 0; r < ROWS; ++r) out[(row0 + r) * C2 + tid] = acc2[r];
    }
}

// ---------------- final 3-layer MLP: 67 -> 64 (tanh) -> 64 (tanh) -> 3
template<int ROWS>
__global__ __launch_bounds__(64) void mlp_final_kernel(
    const float* __restrict__ in,
    const float* __restrict__ Wa, const float* __restrict__ ba,
    const float* __restrict__ Wb, const float* __restrict__ bb,
    const float* __restrict__ Wc, const float* __restrict__ bc,
    float* __restrict__ out, int N)
{
    constexpr int K1 = 67, C = 64;
    __shared__ float xt[ROWS * K1];
    __shared__ float h1[ROWS * C];
    __shared__ float h2[ROWS * 65];   // pad to 65 to kill bank conflicts in layer 3
    const int tid = threadIdx.x;
    const int row0 = blockIdx.x * ROWS;

    for (int f = tid; f < ROWS * K1; f += C)
        xt[f] = in[row0 * K1 + f];
    __syncthreads();

    float acc[ROWS];
    #pragma unroll
    for (int r = 0; r < ROWS; ++r) acc[r] = ba[tid];
    for (int k = 0; k < K1; ++k) {
        const float wv = Wa[tid * K1 + k];
        #pragma unroll
        for (int r = 0; r < ROWS; ++r) acc[r] += xt[r * K1 + k] * wv;
    }
    #pragma unroll
    for (int r = 0; r < ROWS; ++r) h1[r * C + tid] = tanhf(acc[r]);
    __syncthreads();

    float acc2[ROWS];
    #pragma unroll
    for (int r = 0; r < ROWS; ++r) acc2[r] = bb[tid];
    for (int k = 0; k < C; ++k) {
        const float wv = Wb[tid * C + k];
        #pragma unroll
        for (int r = 0; r < ROWS; ++r) acc2[r] += h1[r * C + k] * wv;
    }
    #pragma unroll
    for (int r = 0; r < ROWS; ++r) h2[r * 65 + tid] = tanhf(acc2[r]);
    __syncthreads();

    if (tid < ROWS * 3) {
        const int r = tid / 3, o = tid - r * 3;
        float a = bc[o];
        for (int k = 0; k < C; ++k) a += h2[r * 65 + k] * Wc[o * C + k];
        out[(row0 + r) * 3 + o] = a;
    }
}

extern "C" void kernel_launch(void* const* d_in, const int* in_sizes, int n_in,
                              void* d_out, int out_size, void* d_ws, size_t ws_size,
                              hipStream_t stream)
{
    const float* x       = (const float*)d_in[0];
    const float* pos     = (const float*)d_in[1];
    const float* x_skip2 = (const float*)d_in[3];
    const float* pos2    = (const float*)d_in[4];
    const float* x_skip1 = (const float*)d_in[6];
    const float* pos1    = (const float*)d_in[7];
    const float* x_skip0 = (const float*)d_in[9];
    const float* pos0    = (const float*)d_in[10];
    const float* W3a = (const float*)d_in[12]; const float* b3a = (const float*)d_in[13];
    const float* W3b = (const float*)d_in[14]; const float* b3b = (const float*)d_in[15];
    const float* W2a = (const float*)d_in[16]; const float* b2a = (const float*)d_in[17];
    const float* W2b = (const float*)d_in[18]; const float* b2b = (const float*)d_in[19];
    const float* W1a = (const float*)d_in[20]; const float* b1a = (const float*)d_in[21];
    const float* W1b = (const float*)d_in[22]; const float* b1b = (const float*)d_in[23];
    const float* W1c = (const float*)d_in[24]; const float* b1c = (const float*)d_in[25];

    // ws layout (floats): buf1 = max(4096*384, 16384*192, 65536*67) = 65536*67
    //                     buf2 = max(4096*128, 16384*64)            = 16384*64
    float* buf1 = (float*)d_ws;
    float* buf2 = buf1 + (size_t)65536 * 67;

    // level 3
    knn3_kernel<<<4096, 64, 0, stream>>>(x, pos, pos2, x_skip2, buf1);
    mlp2_kernel<384,128,128,16><<<4096/16, 128, 0, stream>>>(buf1, W3a, b3a, W3b, b3b, buf2, 4096);
    // level 2
    knn2_kernel<<<16384, 64, 0, stream>>>(buf2, pos2, pos1, x_skip1, buf1);
    mlp2_kernel<192,64,64,16><<<16384/16, 64, 0, stream>>>(buf1, W2a, b2a, W2b, b2b, buf2, 16384);
    // level 1
    knn1_kernel<<<65536, 64, 0, stream>>>(buf2, pos1, pos0, x_skip0, buf1);
    mlp_final_kernel<16><<<65536/16, 64, 0, stream>>>(buf1, W1a, b1a, W1b, b1b, W1c, b1c,
                                                      (float*)d_out, 65536);
}

// Round 3
// 362.062 us; speedup vs baseline: 1.3577x; 1.3577x over previous
//
#include <hip/hip_runtime.h>
#include <math.h>

#define DEV __device__ __forceinline__

typedef unsigned long long u64;
typedef unsigned u32;

// monotone map: float bits -> u32 preserving < order (handles negatives)
DEV u32 fmap(float f) {
    u32 b = __float_as_uint(f);
    return b ^ (u32)(((int)b >> 31) | 0x80000000);
}
// recover d2 (only needed when d2 >= 0; negatives clamp to 1e-16 anyway)
DEV float funmap(u32 m) {
    return (m & 0x80000000u) ? __uint_as_float(m ^ 0x80000000u) : -1.f;
}
DEV u64 make_key(float d2, int idx) { return ((u64)fmap(d2) << 10) | (u32)idx; }

DEV u64 umin64(u64 a, u64 b) { return a < b ? a : b; }

DEV u64 shfl_xor_u64(u64 k, int off) {
    u32 lo = (u32)k, hi = (u32)(k >> 32);
    lo = (u32)__shfl_xor((int)lo, off, 64);
    hi = (u32)__shfl_xor((int)hi, off, 64);
    return ((u64)hi << 32) | lo;
}
DEV u64 wave_min_u64(u64 v) {
    #pragma unroll
    for (int off = 32; off; off >>= 1)
        v = umin64(v, shfl_xor_u64(v, off));
    return v;
}
DEV float key_weight(u64 k) {
    return __builtin_amdgcn_rcpf(fmaxf(funmap((u32)(k >> 10)), 1e-16f));
}
DEV int key_row(u64 k) {
    return __builtin_amdgcn_readfirstlane((int)((u32)k & 1023u));
}
#define KMAX 0xFFFFFFFFFFFFFFFFull

// ---------------- level 3: k=4, 64 src/graph, C=256, concat 128 -> out [4096,384]
__global__ __launch_bounds__(64) void knn3_kernel(
    const float* __restrict__ x, const float* __restrict__ pos_s,
    const float* __restrict__ pos_t, const float* __restrict__ x_skip,
    float* __restrict__ out)
{
    const int t = blockIdx.x, lane = threadIdx.x;
    const int g = t >> 8, sbase = g << 6;   // 256 tgts/graph, 64 srcs/graph
    const float qx = pos_t[t*3+0], qy = pos_t[t*3+1], qz = pos_t[t*3+2];
    const float qq = qx*qx + qy*qy + qz*qz;
    const int s = sbase + lane;
    const float px = pos_s[s*3+0], py = pos_s[s*3+1], pz = pos_s[s*3+2];
    const u64 key = make_key(qq + px*px + py*py + pz*pz
                             - 2.f*(qx*px + qy*py + qz*pz), lane);

    float w[4]; int row[4]; float wsum = 0.f;
    u64 gprev = 0;
    #pragma unroll
    for (int j = 0; j < 4; ++j) {
        gprev = wave_min_u64(key > gprev ? key : KMAX);
        w[j] = key_weight(gprev);
        row[j] = sbase + key_row(gprev);
        wsum += w[j];
    }
    const float inv = 1.f / wsum;
    float y0 = 0.f, y1 = 0.f, y2 = 0.f, y3 = 0.f;
    #pragma unroll
    for (int j = 0; j < 4; ++j) {
        const float* xr = x + (size_t)row[j] * 256;
        y0 += w[j] * xr[lane];
        y1 += w[j] * xr[lane + 64];
        y2 += w[j] * xr[lane + 128];
        y3 += w[j] * xr[lane + 192];
    }
    out[t*384 + lane]       = y0 * inv;
    out[t*384 + lane + 64]  = y1 * inv;
    out[t*384 + lane + 128] = y2 * inv;
    out[t*384 + lane + 192] = y3 * inv;
    out[t*384 + 256 + lane]      = x_skip[t*128 + lane];
    out[t*384 + 256 + 64 + lane] = x_skip[t*128 + 64 + lane];
}

// ---------------- level 2: k=8, 256 src/graph, C=128, concat 64 -> out [16384,192]
__global__ __launch_bounds__(64) void knn2_kernel(
    const float* __restrict__ xsrc, const float* __restrict__ pos_s,
    const float* __restrict__ pos_t, const float* __restrict__ x_skip,
    float* __restrict__ out)
{
    const int t = blockIdx.x, lane = threadIdx.x;
    const int g = t >> 10, sbase = g << 8;  // 1024 tgts/graph, 256 srcs/graph
    const float qx = pos_t[t*3+0], qy = pos_t[t*3+1], qz = pos_t[t*3+2];
    const float qq = qx*qx + qy*qy + qz*qz;
    u64 key[4];
    #pragma unroll
    for (int m = 0; m < 4; ++m) {
        const int li = lane + m*64;
        const int s = sbase + li;
        const float px = pos_s[s*3+0], py = pos_s[s*3+1], pz = pos_s[s*3+2];
        key[m] = make_key(qq + px*px + py*py + pz*pz
                          - 2.f*(qx*px + qy*py + qz*pz), li);
    }
    float w[8]; int row[8]; float wsum = 0.f;
    u64 gprev = 0;
    #pragma unroll
    for (int j = 0; j < 8; ++j) {
        u64 c0 = umin64(key[0] > gprev ? key[0] : KMAX,
                        key[1] > gprev ? key[1] : KMAX);
        u64 c1 = umin64(key[2] > gprev ? key[2] : KMAX,
                        key[3] > gprev ? key[3] : KMAX);
        gprev = wave_min_u64(umin64(c0, c1));
        w[j] = key_weight(gprev);
        row[j] = sbase + key_row(gprev);
        wsum += w[j];
    }
    const float inv = 1.f / wsum;
    float y0 = 0.f, y1 = 0.f;
    #pragma unroll
    for (int j = 0; j < 8; ++j) {
        const float* xr = xsrc + (size_t)row[j] * 128;
        y0 += w[j] * xr[lane];
        y1 += w[j] * xr[lane + 64];
    }
    out[t*192 + lane]      = y0 * inv;
    out[t*192 + lane + 64] = y1 * inv;
    out[t*192 + 128 + lane] = x_skip[t*64 + lane];
}

// ---------------- level 1: k=16, 1024 src/graph, C=64, concat 3 -> out [65536,67]
__global__ __launch_bounds__(64) void knn1_kernel(
    const float* __restrict__ xsrc, const float* __restrict__ pos_s,
    const float* __restrict__ pos_t, const float* __restrict__ x_skip,
    float* __restrict__ out)
{
    const int t = blockIdx.x, lane = threadIdx.x;
    const int g = t >> 12, sbase = g << 10; // 4096 tgts/graph, 1024 srcs/graph
    const float qx = pos_t[t*3+0], qy = pos_t[t*3+1], qz = pos_t[t*3+2];
    const float qq = qx*qx + qy*qy + qz*qz;
    u64 key[16];
    #pragma unroll
    for (int m = 0; m < 16; ++m) {
        const int li = lane + m*64;
        const int s = sbase + li;
        const float px = pos_s[s*3+0], py = pos_s[s*3+1], pz = pos_s[s*3+2];
        key[m] = make_key(qq + px*px + py*py + pz*pz
                          - 2.f*(qx*px + qy*py + qz*pz), li);
    }
    float w[16]; int row[16]; float wsum = 0.f;
    u64 gprev = 0;
    #pragma unroll
    for (int j = 0; j < 16; ++j) {
        u64 c0 = KMAX, c1 = KMAX, c2 = KMAX, c3 = KMAX;
        #pragma unroll
        for (int m = 0; m < 16; m += 4) {
            c0 = umin64(c0, key[m+0] > gprev ? key[m+0] : KMAX);
            c1 = umin64(c1, key[m+1] > gprev ? key[m+1] : KMAX);
            c2 = umin64(c2, key[m+2] > gprev ? key[m+2] : KMAX);
            c3 = umin64(c3, key[m+3] > gprev ? key[m+3] : KMAX);
        }
        gprev = wave_min_u64(umin64(umin64(c0, c1), umin64(c2, c3)));
        w[j] = key_weight(gprev);
        row[j] = sbase + key_row(gprev);
        wsum += w[j];
    }
    const float inv = 1.f / wsum;
    float y = 0.f;
    #pragma unroll
    for (int j = 0; j < 16; ++j)
        y += w[j] * xsrc[(size_t)row[j] * 64 + lane];
    out[t*67 + lane] = y * inv;
    if (lane < 3) out[t*67 + 64 + lane] = x_skip[t*3 + lane];
}

// ---------------- fused 2-layer MLP: out = (tanh(in*Wa^T+ba))*Wb^T+bb
template<int K1, int C1, int C2, int ROWS>
__global__ void mlp2_kernel(
    const float* __restrict__ in, const float* __restrict__ Wa,
    const float* __restrict__ ba, const float* __restrict__ Wb,
    const float* __restrict__ bb, float* __restrict__ out, int N)
{
    __shared__ float xt[ROWS * K1];
    __shared__ float h1[ROWS * C1];
    const int tid = threadIdx.x;
    const int row0 = blockIdx.x * ROWS;

    for (int f = tid; f < ROWS * K1; f += C1)
        xt[f] = in[row0 * K1 + f];
    __syncthreads();

    float acc[ROWS];
    #pragma unroll
    for (int r = 0; r < ROWS; ++r) acc[r] = ba[tid];
    for (int k = 0; k < K1; ++k) {
        const float wv = Wa[tid * K1 + k];
        #pragma unroll
        for (int r = 0; r < ROWS; ++r) acc[r] += xt[r * K1 + k] * wv;
    }
    #pragma unroll
    for (int r = 0; r < ROWS; ++r) h1[r * C1 + tid] = tanhf(acc[r]);
    __syncthreads();

    if (tid < C2) {
        float acc2[ROWS];
        #pragma unroll
        for (int r = 0; r < ROWS; ++r) acc2[r] = bb[tid];
        for (int k = 0; k < C1; ++k) {
            const float wv = Wb[tid * C1 + k];
            #pragma unroll
            for (int r = 0; r < ROWS; ++r) acc2[r] += h1[r * C1 + k] * wv;
        }
        #pragma unroll
        for (int r = 0; r < ROWS; ++r) out[(row0 + r) * C2 + tid] = acc2[r];
    }
}

// ---------------- final 3-layer MLP: 67 -> 64 (tanh) -> 64 (tanh) -> 3
template<int ROWS>
__global__ __launch_bounds__(64) void mlp_final_kernel(
    const float* __restrict__ in,
    const float* __restrict__ Wa, const float* __restrict__ ba,
    const float* __restrict__ Wb, const float* __restrict__ bb,
    const float* __restrict__ Wc, const float* __restrict__ bc,
    float* __restrict__ out, int N)
{
    constexpr int K1 = 67, C = 64;
    __shared__ float xt[ROWS * K1];
    __shared__ float h1[ROWS * C];
    __shared__ float h2[ROWS * 65];
    const int tid = threadIdx.x;
    const int row0 = blockIdx.x * ROWS;

    for (int f = tid; f < ROWS * K1; f += C)
        xt[f] = in[row0 * K1 + f];
    __syncthreads();

    float acc[ROWS];
    #pragma unroll
    for (int r = 0; r < ROWS; ++r) acc[r] = ba[tid];
    for (int k = 0; k < K1; ++k) {
        const float wv = Wa[tid * K1 + k];
        #pragma unroll
        for (int r = 0; r < ROWS; ++r) acc[r] += xt[r * K1 + k] * wv;
    }
    #pragma unroll
    for (int r = 0; r < ROWS; ++r) h1[r * C + tid] = tanhf(acc[r]);
    __syncthreads();

    float acc2[ROWS];
    #pragma unroll
    for (int r = 0; r < ROWS; ++r) acc2[r] = bb[tid];
    for (int k = 0; k < C; ++k) {
        const float wv = Wb[tid * C + k];
        #pragma unroll
        for (int r = 0; r < ROWS; ++r) acc2[r] += h1[r * C + k] * wv;
    }
    #pragma unroll
    for (int r = 0; r < ROWS; ++r) h2[r * 65 + tid] = tanhf(acc2[r]);
    __syncthreads();

    if (tid < ROWS * 3) {
        const int r = tid / 3, o = tid - r * 3;
        float a = bc[o];
        for (int k = 0; k < C; ++k) a += h2[r * 65 + k] * Wc[o * C + k];
        out[(row0 + r) * 3 + o] = a;
    }
}

extern "C" void kernel_launch(void* const* d_in, const int* in_sizes, int n_in,
                              void* d_out, int out_size, void* d_ws, size_t ws_size,
                              hipStream_t stream)
{
    const float* x       = (const float*)d_in[0];
    const float* pos     = (const float*)d_in[1];
    const float* x_skip2 = (const float*)d_in[3];
    const float* pos2    = (const float*)d_in[4];
    const float* x_skip1 = (const float*)d_in[6];
    const float* pos1    = (const float*)d_in[7];
    const float* x_skip0 = (const float*)d_in[9];
    const float* pos0    = (const float*)d_in[10];
    const float* W3a = (const float*)d_in[12]; const float* b3a = (const float*)d_in[13];
    const float* W3b = (const float*)d_in[14]; const float* b3b = (const float*)d_in[15];
    const float* W2a = (const float*)d_in[16]; const float* b2a = (const float*)d_in[17];
    const float* W2b = (const float*)d_in[18]; const float* b2b = (const float*)d_in[19];
    const float* W1a = (const float*)d_in[20]; const float* b1a = (const float*)d_in[21];
    const float* W1b = (const float*)d_in[22]; const float* b1b = (const float*)d_in[23];
    const float* W1c = (const float*)d_in[24]; const float* b1c = (const float*)d_in[25];

    float* buf1 = (float*)d_ws;
    float* buf2 = buf1 + (size_t)65536 * 67;

    // level 3
    knn3_kernel<<<4096, 64, 0, stream>>>(x, pos, pos2, x_skip2, buf1);
    mlp2_kernel<384,128,128,16><<<4096/16, 128, 0, stream>>>(buf1, W3a, b3a, W3b, b3b, buf2, 4096);
    // level 2
    knn2_kernel<<<16384, 64, 0, stream>>>(buf2, pos2, pos1, x_skip1, buf1);
    mlp2_kernel<192,64,64,16><<<16384/16, 64, 0, stream>>>(buf1, W2a, b2a, W2b, b2b, buf2, 16384);
    // level 1
    knn1_kernel<<<65536, 64, 0, stream>>>(buf2, pos1, pos0, x_skip0, buf1);
    mlp_final_kernel<16><<<65536/16, 64, 0, stream>>>(buf1, W1a, b1a, W1b, b1b, W1c, b1c,
                                                      (float*)d_out, 65536);
}

// Round 4
// 319.103 us; speedup vs baseline: 1.5405x; 1.1346x over previous
//
#include <hip/hip_runtime.h>
#include <math.h>

#define DEV __device__ __forceinline__

typedef unsigned long long u64;
typedef unsigned u32;

// monotone map: float bits -> u32 preserving < order (handles negatives)
DEV u32 fmap(float f) {
    u32 b = __float_as_uint(f);
    return b ^ (u32)(((int)b >> 31) | 0x80000000);
}
// exact inverse of fmap
DEV float funmap(u32 m) {
    u32 b = (m & 0x80000000u) ? (m ^ 0x80000000u) : ~m;
    return __uint_as_float(b);
}

// ================= binary-search kNN core (per-wave, M candidates/lane) ======
// Finds F = k-th smallest fmap value among the wave's M*64 candidates,
// then walks selected candidates (scalar loop, k hits total).

// ---------------- level 1: k=16, 1024 src/graph, C=64, concat 3 -> out [65536,67]
__global__ __launch_bounds__(64) void knn1_kernel(
    const float* __restrict__ xsrc, const float* __restrict__ pos_s,
    const float* __restrict__ pos_t, const float* __restrict__ x_skip,
    float* __restrict__ out)
{
    const int t = blockIdx.x, lane = threadIdx.x;
    const int g = t >> 12, sbase = g << 10; // 4096 tgts/graph, 1024 srcs/graph
    const float qx = pos_t[t*3+0], qy = pos_t[t*3+1], qz = pos_t[t*3+2];
    const float qq = qx*qx + qy*qy + qz*qz;
    u32 fm[16];
    #pragma unroll
    for (int m = 0; m < 16; ++m) {
        const int s = sbase + lane + m*64;
        const float px = pos_s[s*3+0], py = pos_s[s*3+1], pz = pos_s[s*3+2];
        fm[m] = fmap(qq + px*px + py*py + pz*pz
                     - 2.f*(qx*px + qy*py + qz*pz));
    }
    // ---- binary search for 16th smallest fmap
    u32 F = 0u;
    for (int b = 31; b >= 0; --b) {
        const u32 trial = F | (1u << b);
        int c = 0;
        #pragma unroll
        for (int m = 0; m < 16; ++m)
            c += (int)__popcll(__ballot(fm[m] < trial));
        if (c < 16) F = trial;
    }
    // ---- extraction: all fmap<F, then lowest-index ties fmap==F
    float wsum = 0.f, y = 0.f;
    int need = 16;
    #pragma unroll
    for (int m = 0; m < 16; ++m) {
        u64 mask = __ballot(fm[m] < F);
        while (mask) {
            const int l = __ffsll((long long)mask) - 1; mask &= mask - 1;
            const float d2 = funmap((u32)__builtin_amdgcn_readlane((int)fm[m], l));
            const float w = __builtin_amdgcn_rcpf(fmaxf(d2, 1e-16f));
            const int row = sbase + l + m*64;
            wsum += w; y += w * xsrc[(size_t)row * 64 + lane];
            --need;
        }
    }
    #pragma unroll
    for (int m = 0; m < 16; ++m) {
        if (need > 0) {
            u64 mask = __ballot(fm[m] == F);
            while (mask && need > 0) {
                const int l = __ffsll((long long)mask) - 1; mask &= mask - 1;
                const float d2 = funmap(F);
                const float w = __builtin_amdgcn_rcpf(fmaxf(d2, 1e-16f));
                const int row = sbase + l + m*64;
                wsum += w; y += w * xsrc[(size_t)row * 64 + lane];
                --need;
            }
        }
    }
    out[t*67 + lane] = y * (1.f / wsum);
    if (lane < 3) out[t*67 + 64 + lane] = x_skip[t*3 + lane];
}

// ---------------- level 2: k=8, 256 src/graph, C=128, concat 64 -> out [16384,192]
__global__ __launch_bounds__(64) void knn2_kernel(
    const float* __restrict__ xsrc, const float* __restrict__ pos_s,
    const float* __restrict__ pos_t, const float* __restrict__ x_skip,
    float* __restrict__ out)
{
    const int t = blockIdx.x, lane = threadIdx.x;
    const int g = t >> 10, sbase = g << 8;  // 1024 tgts/graph, 256 srcs/graph
    const float qx = pos_t[t*3+0], qy = pos_t[t*3+1], qz = pos_t[t*3+2];
    const float qq = qx*qx + qy*qy + qz*qz;
    u32 fm[4];
    #pragma unroll
    for (int m = 0; m < 4; ++m) {
        const int s = sbase + lane + m*64;
        const float px = pos_s[s*3+0], py = pos_s[s*3+1], pz = pos_s[s*3+2];
        fm[m] = fmap(qq + px*px + py*py + pz*pz
                     - 2.f*(qx*px + qy*py + qz*pz));
    }
    u32 F = 0u;
    for (int b = 31; b >= 0; --b) {
        const u32 trial = F | (1u << b);
        int c = 0;
        #pragma unroll
        for (int m = 0; m < 4; ++m)
            c += (int)__popcll(__ballot(fm[m] < trial));
        if (c < 8) F = trial;
    }
    float wsum = 0.f, y0 = 0.f, y1 = 0.f;
    int need = 8;
    #pragma unroll
    for (int m = 0; m < 4; ++m) {
        u64 mask = __ballot(fm[m] < F);
        while (mask) {
            const int l = __ffsll((long long)mask) - 1; mask &= mask - 1;
            const float d2 = funmap((u32)__builtin_amdgcn_readlane((int)fm[m], l));
            const float w = __builtin_amdgcn_rcpf(fmaxf(d2, 1e-16f));
            const float* xr = xsrc + (size_t)(sbase + l + m*64) * 128;
            wsum += w; y0 += w * xr[lane]; y1 += w * xr[lane + 64];
            --need;
        }
    }
    #pragma unroll
    for (int m = 0; m < 4; ++m) {
        if (need > 0) {
            u64 mask = __ballot(fm[m] == F);
            while (mask && need > 0) {
                const int l = __ffsll((long long)mask) - 1; mask &= mask - 1;
                const float d2 = funmap(F);
                const float w = __builtin_amdgcn_rcpf(fmaxf(d2, 1e-16f));
                const float* xr = xsrc + (size_t)(sbase + l + m*64) * 128;
                wsum += w; y0 += w * xr[lane]; y1 += w * xr[lane + 64];
                --need;
            }
        }
    }
    const float inv = 1.f / wsum;
    out[t*192 + lane]      = y0 * inv;
    out[t*192 + lane + 64] = y1 * inv;
    out[t*192 + 128 + lane] = x_skip[t*64 + lane];
}

// ---------------- level 3 (unchanged R2 path): k=4, 64 src/graph, C=256 -> out [4096,384]
DEV u64 umin64(u64 a, u64 b) { return a < b ? a : b; }
DEV u64 shfl_xor_u64(u64 k, int off) {
    u32 lo = (u32)k, hi = (u32)(k >> 32);
    lo = (u32)__shfl_xor((int)lo, off, 64);
    hi = (u32)__shfl_xor((int)hi, off, 64);
    return ((u64)hi << 32) | lo;
}
DEV u64 wave_min_u64(u64 v) {
    #pragma unroll
    for (int off = 32; off; off >>= 1)
        v = umin64(v, shfl_xor_u64(v, off));
    return v;
}
DEV u64 make_key(float d2, int idx) { return ((u64)fmap(d2) << 10) | (u32)idx; }
DEV float key_weight(u64 k) {
    return __builtin_amdgcn_rcpf(fmaxf(funmap((u32)(k >> 10)), 1e-16f));
}
DEV int key_row(u64 k) {
    return __builtin_amdgcn_readfirstlane((int)((u32)k & 1023u));
}
#define KMAX 0xFFFFFFFFFFFFFFFFull

__global__ __launch_bounds__(64) void knn3_kernel(
    const float* __restrict__ x, const float* __restrict__ pos_s,
    const float* __restrict__ pos_t, const float* __restrict__ x_skip,
    float* __restrict__ out)
{
    const int t = blockIdx.x, lane = threadIdx.x;
    const int g = t >> 8, sbase = g << 6;   // 256 tgts/graph, 64 srcs/graph
    const float qx = pos_t[t*3+0], qy = pos_t[t*3+1], qz = pos_t[t*3+2];
    const float qq = qx*qx + qy*qy + qz*qz;
    const int s = sbase + lane;
    const float px = pos_s[s*3+0], py = pos_s[s*3+1], pz = pos_s[s*3+2];
    const u64 key = make_key(qq + px*px + py*py + pz*pz
                             - 2.f*(qx*px + qy*py + qz*pz), lane);

    float w[4]; int row[4]; float wsum = 0.f;
    u64 gprev = 0;
    #pragma unroll
    for (int j = 0; j < 4; ++j) {
        gprev = wave_min_u64(key > gprev ? key : KMAX);
        w[j] = key_weight(gprev);
        row[j] = sbase + key_row(gprev);
        wsum += w[j];
    }
    const float inv = 1.f / wsum;
    float y0 = 0.f, y1 = 0.f, y2 = 0.f, y3 = 0.f;
    #pragma unroll
    for (int j = 0; j < 4; ++j) {
        const float* xr = x + (size_t)row[j] * 256;
        y0 += w[j] * xr[lane];
        y1 += w[j] * xr[lane + 64];
        y2 += w[j] * xr[lane + 128];
        y3 += w[j] * xr[lane + 192];
    }
    out[t*384 + lane]       = y0 * inv;
    out[t*384 + lane + 64]  = y1 * inv;
    out[t*384 + lane + 128] = y2 * inv;
    out[t*384 + lane + 192] = y3 * inv;
    out[t*384 + 256 + lane]      = x_skip[t*128 + lane];
    out[t*384 + 256 + 64 + lane] = x_skip[t*128 + 64 + lane];
}

// ---------------- fused 2-layer MLP: out = (tanh(in*Wa^T+ba))*Wb^T+bb
template<int K1, int C1, int C2, int ROWS>
__global__ void mlp2_kernel(
    const float* __restrict__ in, const float* __restrict__ Wa,
    const float* __restrict__ ba, const float* __restrict__ Wb,
    const float* __restrict__ bb, float* __restrict__ out, int N)
{
    __shared__ float xt[ROWS * K1];
    __shared__ float h1[ROWS * C1];
    const int tid = threadIdx.x;
    const int row0 = blockIdx.x * ROWS;

    for (int f = tid; f < ROWS * K1; f += C1)
        xt[f] = in[row0 * K1 + f];
    __syncthreads();

    float acc[ROWS];
    #pragma unroll
    for (int r = 0; r < ROWS; ++r) acc[r] = ba[tid];
    for (int k = 0; k < K1; ++k) {
        const float wv = Wa[tid * K1 + k];
        #pragma unroll
        for (int r = 0; r < ROWS; ++r) acc[r] += xt[r * K1 + k] * wv;
    }
    #pragma unroll
    for (int r = 0; r < ROWS; ++r) h1[r * C1 + tid] = tanhf(acc[r]);
    __syncthreads();

    if (tid < C2) {
        float acc2[ROWS];
        #pragma unroll
        for (int r = 0; r < ROWS; ++r) acc2[r] = bb[tid];
        for (int k = 0; k < C1; ++k) {
            const float wv = Wb[tid * C1 + k];
            #pragma unroll
            for (int r = 0; r < ROWS; ++r) acc2[r] += h1[r * C1 + k] * wv;
        }
        #pragma unroll
        for (int r = 0; r < ROWS; ++r) out[(row0 + r) * C2 + tid] = acc2[r];
    }
}

// ---------------- final 3-layer MLP: 67 -> 64 (tanh) -> 64 (tanh) -> 3
template<int ROWS>
__global__ __launch_bounds__(64) void mlp_final_kernel(
    const float* __restrict__ in,
    const float* __restrict__ Wa, const float* __restrict__ ba,
    const float* __restrict__ Wb, const float* __restrict__ bb,
    const float* __restrict__ Wc, const float* __restrict__ bc,
    float* __restrict__ out, int N)
{
    constexpr int K1 = 67, C = 64;
    __shared__ float xt[ROWS * K1];
    __shared__ float h1[ROWS * C];
    __shared__ float h2[ROWS * 65];
    const int tid = threadIdx.x;
    const int row0 = blockIdx.x * ROWS;

    for (int f = tid; f < ROWS * K1; f += C)
        xt[f] = in[row0 * K1 + f];
    __syncthreads();

    float acc[ROWS];
    #pragma unroll
    for (int r = 0; r < ROWS; ++r) acc[r] = ba[tid];
    for (int k = 0; k < K1; ++k) {
        const float wv = Wa[tid * K1 + k];
        #pragma unroll
        for (int r = 0; r < ROWS; ++r) acc[r] += xt[r * K1 + k] * wv;
    }
    #pragma unroll
    for (int r = 0; r < ROWS; ++r) h1[r * C + tid] = tanhf(acc[r]);
    __syncthreads();

    float acc2[ROWS];
    #pragma unroll
    for (int r = 0; r < ROWS; ++r) acc2[r] = bb[tid];
    for (int k = 0; k < C; ++k) {
        const float wv = Wb[tid * C + k];
        #pragma unroll
        for (int r = 0; r < ROWS; ++r) acc2[r] += h1[r * C + k] * wv;
    }
    #pragma unroll
    for (int r = 0; r < ROWS; ++r) h2[r * 65 + tid] = tanhf(acc2[r]);
    __syncthreads();

    if (tid < ROWS * 3) {
        const int r = tid / 3, o = tid - r * 3;
        float a = bc[o];
        for (int k = 0; k < C; ++k) a += h2[r * 65 + k] * Wc[o * C + k];
        out[(row0 + r) * 3 + o] = a;
    }
}

extern "C" void kernel_launch(void* const* d_in, const int* in_sizes, int n_in,
                              void* d_out, int out_size, void* d_ws, size_t ws_size,
                              hipStream_t stream)
{
    const float* x       = (const float*)d_in[0];
    const float* pos     = (const float*)d_in[1];
    const float* x_skip2 = (const float*)d_in[3];
    const float* pos2    = (const float*)d_in[4];
    const float* x_skip1 = (const float*)d_in[6];
    const float* pos1    = (const float*)d_in[7];
    const float* x_skip0 = (const float*)d_in[9];
    const float* pos0    = (const float*)d_in[10];
    const float* W3a = (const float*)d_in[12]; const float* b3a = (const float*)d_in[13];
    const float* W3b = (const float*)d_in[14]; const float* b3b = (const float*)d_in[15];
    const float* W2a = (const float*)d_in[16]; const float* b2a = (const float*)d_in[17];
    const float* W2b = (const float*)d_in[18]; const float* b2b = (const float*)d_in[19];
    const float* W1a = (const float*)d_in[20]; const float* b1a = (const float*)d_in[21];
    const float* W1b = (const float*)d_in[22]; const float* b1b = (const float*)d_in[23];
    const float* W1c = (const float*)d_in[24]; const float* b1c = (const float*)d_in[25];

    float* buf1 = (float*)d_ws;
    float* buf2 = buf1 + (size_t)65536 * 67;

    // level 3
    knn3_kernel<<<4096, 64, 0, stream>>>(x, pos, pos2, x_skip2, buf1);
    mlp2_kernel<384,128,128,16><<<4096/16, 128, 0, stream>>>(buf1, W3a, b3a, W3b, b3b, buf2, 4096);
    // level 2
    knn2_kernel<<<16384, 64, 0, stream>>>(buf2, pos2, pos1, x_skip1, buf1);
    mlp2_kernel<192,64,64,16><<<16384/16, 64, 0, stream>>>(buf1, W2a, b2a, W2b, b2b, buf2, 16384);
    // level 1
    knn1_kernel<<<65536, 64, 0, stream>>>(buf2, pos1, pos0, x_skip0, buf1);
    mlp_final_kernel<16><<<65536/16, 64, 0, stream>>>(buf1, W1a, b1a, W1b, b1b, W1c, b1c,
                                                      (float*)d_out, 65536);
}

// Round 5
// 314.166 us; speedup vs baseline: 1.5647x; 1.0157x over previous
//
#include <hip/hip_runtime.h>
#include <math.h>

#define DEV __device__ __forceinline__

typedef unsigned long long u64;
typedef unsigned u32;

// monotone map: float bits -> u32 preserving < order (handles negatives)
DEV u32 fmap(float f) {
    u32 b = __float_as_uint(f);
    return b ^ (u32)(((int)b >> 31) | 0x80000000);
}
// exact inverse of fmap
DEV float funmap(u32 m) {
    u32 b = (m & 0x80000000u) ? (m ^ 0x80000000u) : ~m;
    return __uint_as_float(b);
}

// ---------------- level 1: k=16, 1024 src/graph, C=64, concat 3 -> out [65536,67]
// 4 targets per 256-thread block, one per wave.
__global__ __launch_bounds__(256) void knn1_kernel(
    const float* __restrict__ xsrc, const float* __restrict__ pos_s,
    const float* __restrict__ pos_t, const float* __restrict__ x_skip,
    float* __restrict__ out)
{
    const int lane = threadIdx.x & 63;
    const int t = blockIdx.x * 4 + (threadIdx.x >> 6);
    const int g = t >> 12, sbase = g << 10; // 4096 tgts/graph, 1024 srcs/graph
    const float qx = pos_t[t*3+0], qy = pos_t[t*3+1], qz = pos_t[t*3+2];
    const float qq = qx*qx + qy*qy + qz*qz;
    u32 fm[16];
    #pragma unroll
    for (int m = 0; m < 16; ++m) {
        const int s = sbase + lane + m*64;
        const float px = pos_s[s*3+0], py = pos_s[s*3+1], pz = pos_s[s*3+2];
        fm[m] = fmap(qq + px*px + py*py + pz*pz
                     - 2.f*(qx*px + qy*py + qz*pz));
    }
    // ---- binary search for 16th smallest fmap (exact, 32 bits)
    u32 F = 0u;
    for (int b = 31; b >= 0; --b) {
        const u32 trial = F | (1u << b);
        int c = 0;
        #pragma unroll
        for (int m = 0; m < 16; ++m)
            c += (int)__popcll(__ballot(fm[m] < trial));
        if (c < 16) F = trial;
    }
    // ---- extraction: all fmap<F, then lowest-index ties fmap==F
    float wsum = 0.f, y = 0.f;
    int need = 16;
    #pragma unroll
    for (int m = 0; m < 16; ++m) {
        u64 mask = __ballot(fm[m] < F);
        while (mask) {
            const int l = __ffsll((long long)mask) - 1; mask &= mask - 1;
            const float d2 = funmap((u32)__builtin_amdgcn_readlane((int)fm[m], l));
            const float w = __builtin_amdgcn_rcpf(fmaxf(d2, 1e-16f));
            const int row = sbase + l + m*64;
            wsum += w; y += w * xsrc[(size_t)row * 64 + lane];
            --need;
        }
    }
    #pragma unroll
    for (int m = 0; m < 16; ++m) {
        if (need > 0) {
            u64 mask = __ballot(fm[m] == F);
            while (mask && need > 0) {
                const int l = __ffsll((long long)mask) - 1; mask &= mask - 1;
                const float d2 = funmap(F);
                const float w = __builtin_amdgcn_rcpf(fmaxf(d2, 1e-16f));
                const int row = sbase + l + m*64;
                wsum += w; y += w * xsrc[(size_t)row * 64 + lane];
                --need;
            }
        }
    }
    out[t*67 + lane] = y * (1.f / wsum);
    if (lane < 3) out[t*67 + 64 + lane] = x_skip[t*3 + lane];
}

// ---------------- level 2: k=8, 256 src/graph, C=128, concat 64 -> out [16384,192]
__global__ __launch_bounds__(256) void knn2_kernel(
    const float* __restrict__ xsrc, const float* __restrict__ pos_s,
    const float* __restrict__ pos_t, const float* __restrict__ x_skip,
    float* __restrict__ out)
{
    const int lane = threadIdx.x & 63;
    const int t = blockIdx.x * 4 + (threadIdx.x >> 6);
    const int g = t >> 10, sbase = g << 8;  // 1024 tgts/graph, 256 srcs/graph
    const float qx = pos_t[t*3+0], qy = pos_t[t*3+1], qz = pos_t[t*3+2];
    const float qq = qx*qx + qy*qy + qz*qz;
    u32 fm[4];
    #pragma unroll
    for (int m = 0; m < 4; ++m) {
        const int s = sbase + lane + m*64;
        const float px = pos_s[s*3+0], py = pos_s[s*3+1], pz = pos_s[s*3+2];
        fm[m] = fmap(qq + px*px + py*py + pz*pz
                     - 2.f*(qx*px + qy*py + qz*pz));
    }
    u32 F = 0u;
    for (int b = 31; b >= 0; --b) {
        const u32 trial = F | (1u << b);
        int c = 0;
        #pragma unroll
        for (int m = 0; m < 4; ++m)
            c += (int)__popcll(__ballot(fm[m] < trial));
        if (c < 8) F = trial;
    }
    float wsum = 0.f, y0 = 0.f, y1 = 0.f;
    int need = 8;
    #pragma unroll
    for (int m = 0; m < 4; ++m) {
        u64 mask = __ballot(fm[m] < F);
        while (mask) {
            const int l = __ffsll((long long)mask) - 1; mask &= mask - 1;
            const float d2 = funmap((u32)__builtin_amdgcn_readlane((int)fm[m], l));
            const float w = __builtin_amdgcn_rcpf(fmaxf(d2, 1e-16f));
            const float* xr = xsrc + (size_t)(sbase + l + m*64) * 128;
            wsum += w; y0 += w * xr[lane]; y1 += w * xr[lane + 64];
            --need;
        }
    }
    #pragma unroll
    for (int m = 0; m < 4; ++m) {
        if (need > 0) {
            u64 mask = __ballot(fm[m] == F);
            while (mask && need > 0) {
                const int l = __ffsll((long long)mask) - 1; mask &= mask - 1;
                const float d2 = funmap(F);
                const float w = __builtin_amdgcn_rcpf(fmaxf(d2, 1e-16f));
                const float* xr = xsrc + (size_t)(sbase + l + m*64) * 128;
                wsum += w; y0 += w * xr[lane]; y1 += w * xr[lane + 64];
                --need;
            }
        }
    }
    const float inv = 1.f / wsum;
    out[t*192 + lane]      = y0 * inv;
    out[t*192 + lane + 64] = y1 * inv;
    out[t*192 + 128 + lane] = x_skip[t*64 + lane];
}

// ---------------- level 3: k=4, 64 src/graph, C=256 -> out [4096,384]
DEV u64 umin64(u64 a, u64 b) { return a < b ? a : b; }
DEV u64 shfl_xor_u64(u64 k, int off) {
    u32 lo = (u32)k, hi = (u32)(k >> 32);
    lo = (u32)__shfl_xor((int)lo, off, 64);
    hi = (u32)__shfl_xor((int)hi, off, 64);
    return ((u64)hi << 32) | lo;
}
DEV u64 wave_min_u64(u64 v) {
    #pragma unroll
    for (int off = 32; off; off >>= 1)
        v = umin64(v, shfl_xor_u64(v, off));
    return v;
}
DEV u64 make_key(float d2, int idx) { return ((u64)fmap(d2) << 10) | (u32)idx; }
DEV float key_weight(u64 k) {
    return __builtin_amdgcn_rcpf(fmaxf(funmap((u32)(k >> 10)), 1e-16f));
}
DEV int key_row(u64 k) {
    return __builtin_amdgcn_readfirstlane((int)((u32)k & 1023u));
}
#define KMAX 0xFFFFFFFFFFFFFFFFull

__global__ __launch_bounds__(256) void knn3_kernel(
    const float* __restrict__ x, const float* __restrict__ pos_s,
    const float* __restrict__ pos_t, const float* __restrict__ x_skip,
    float* __restrict__ out)
{
    const int lane = threadIdx.x & 63;
    const int t = blockIdx.x * 4 + (threadIdx.x >> 6);
    const int g = t >> 8, sbase = g << 6;   // 256 tgts/graph, 64 srcs/graph
    const float qx = pos_t[t*3+0], qy = pos_t[t*3+1], qz = pos_t[t*3+2];
    const float qq = qx*qx + qy*qy + qz*qz;
    const int s = sbase + lane;
    const float px = pos_s[s*3+0], py = pos_s[s*3+1], pz = pos_s[s*3+2];
    const u64 key = make_key(qq + px*px + py*py + pz*pz
                             - 2.f*(qx*px + qy*py + qz*pz), lane);

    float w[4]; int row[4]; float wsum = 0.f;
    u64 gprev = 0;
    #pragma unroll
    for (int j = 0; j < 4; ++j) {
        gprev = wave_min_u64(key > gprev ? key : KMAX);
        w[j] = key_weight(gprev);
        row[j] = sbase + key_row(gprev);
        wsum += w[j];
    }
    const float inv = 1.f / wsum;
    float y0 = 0.f, y1 = 0.f, y2 = 0.f, y3 = 0.f;
    #pragma unroll
    for (int j = 0; j < 4; ++j) {
        const float* xr = x + (size_t)row[j] * 256;
        y0 += w[j] * xr[lane];
        y1 += w[j] * xr[lane + 64];
        y2 += w[j] * xr[lane + 128];
        y3 += w[j] * xr[lane + 192];
    }
    out[t*384 + lane]       = y0 * inv;
    out[t*384 + lane + 64]  = y1 * inv;
    out[t*384 + lane + 128] = y2 * inv;
    out[t*384 + lane + 192] = y3 * inv;
    out[t*384 + 256 + lane]      = x_skip[t*128 + lane];
    out[t*384 + 256 + 64 + lane] = x_skip[t*128 + 64 + lane];
}

// ---------------- fused 2-layer MLP: out = (tanh(in*Wa^T+ba))*Wb^T+bb
template<int K1, int C1, int C2, int ROWS>
__global__ void mlp2_kernel(
    const float* __restrict__ in, const float* __restrict__ Wa,
    const float* __restrict__ ba, const float* __restrict__ Wb,
    const float* __restrict__ bb, float* __restrict__ out, int N)
{
    __shared__ float xt[ROWS * K1];
    __shared__ float h1[ROWS * C1];
    const int tid = threadIdx.x;
    const int row0 = blockIdx.x * ROWS;

    for (int f = tid; f < ROWS * K1; f += C1)
        xt[f] = in[row0 * K1 + f];
    __syncthreads();

    float acc[ROWS];
    #pragma unroll
    for (int r = 0; r < ROWS; ++r) acc[r] = ba[tid];
    for (int k = 0; k < K1; ++k) {
        const float wv = Wa[tid * K1 + k];
        #pragma unroll
        for (int r = 0; r < ROWS; ++r) acc[r] += xt[r * K1 + k] * wv;
    }
    #pragma unroll
    for (int r = 0; r < ROWS; ++r) h1[r * C1 + tid] = tanhf(acc[r]);
    __syncthreads();

    if (tid < C2) {
        float acc2[ROWS];
        #pragma unroll
        for (int r = 0; r < ROWS; ++r) acc2[r] = bb[tid];
        for (int k = 0; k < C1; ++k) {
            const float wv = Wb[tid * C1 + k];
            #pragma unroll
            for (int r = 0; r < ROWS; ++r) acc2[r] += h1[r * C1 + k] * wv;
        }
        #pragma unroll
        for (int r = 0; r < ROWS; ++r) out[(row0 + r) * C2 + tid] = acc2[r];
    }
}

// ---------------- final 3-layer MLP: 67 -> 64 (tanh) -> 64 (tanh) -> 3
template<int ROWS>
__global__ __launch_bounds__(64) void mlp_final_kernel(
    const float* __restrict__ in,
    const float* __restrict__ Wa, const float* __restrict__ ba,
    const float* __restrict__ Wb, const float* __restrict__ bb,
    const float* __restrict__ Wc, const float* __restrict__ bc,
    float* __restrict__ out, int N)
{
    constexpr int K1 = 67, C = 64;
    __shared__ float xt[ROWS * K1];
    __shared__ float h1[ROWS * C];
    __shared__ float h2[ROWS * 65];
    const int tid = threadIdx.x;
    const int row0 = blockIdx.x * ROWS;

    for (int f = tid; f < ROWS * K1; f += C)
        xt[f] = in[row0 * K1 + f];
    __syncthreads();

    float acc[ROWS];
    #pragma unroll
    for (int r = 0; r < ROWS; ++r) acc[r] = ba[tid];
    for (int k = 0; k < K1; ++k) {
        const float wv = Wa[tid * K1 + k];
        #pragma unroll
        for (int r = 0; r < ROWS; ++r) acc[r] += xt[r * K1 + k] * wv;
    }
    #pragma unroll
    for (int r = 0; r < ROWS; ++r) h1[r * C + tid] = tanhf(acc[r]);
    __syncthreads();

    float acc2[ROWS];
    #pragma unroll
    for (int r = 0; r < ROWS; ++r) acc2[r] = bb[tid];
    for (int k = 0; k < C; ++k) {
        const float wv = Wb[tid * C + k];
        #pragma unroll
        for (int r = 0; r < ROWS; ++r) acc2[r] += h1[r * C + k] * wv;
    }
    #pragma unroll
    for (int r = 0; r < ROWS; ++r) h2[r * 65 + tid] = tanhf(acc2[r]);
    __syncthreads();

    if (tid < ROWS * 3) {
        const int r = tid / 3, o = tid - r * 3;
        float a = bc[o];
        for (int k = 0; k < C; ++k) a += h2[r * 65 + k] * Wc[o * C + k];
        out[(row0 + r) * 3 + o] = a;
    }
}

extern "C" void kernel_launch(void* const* d_in, const int* in_sizes, int n_in,
                              void* d_out, int out_size, void* d_ws, size_t ws_size,
                              hipStream_t stream)
{
    const float* x       = (const float*)d_in[0];
    const float* pos     = (const float*)d_in[1];
    const float* x_skip2 = (const float*)d_in[3];
    const float* pos2    = (const float*)d_in[4];
    const float* x_skip1 = (const float*)d_in[6];
    const float* pos1    = (const float*)d_in[7];
    const float* x_skip0 = (const float*)d_in[9];
    const float* pos0    = (const float*)d_in[10];
    const float* W3a = (const float*)d_in[12]; const float* b3a = (const float*)d_in[13];
    const float* W3b = (const float*)d_in[14]; const float* b3b = (const float*)d_in[15];
    const float* W2a = (const float*)d_in[16]; const float* b2a = (const float*)d_in[17];
    const float* W2b = (const float*)d_in[18]; const float* b2b = (const float*)d_in[19];
    const float* W1a = (const float*)d_in[20]; const float* b1a = (const float*)d_in[21];
    const float* W1b = (const float*)d_in[22]; const float* b1b = (const float*)d_in[23];
    const float* W1c = (const float*)d_in[24]; const float* b1c = (const float*)d_in[25];

    float* buf1 = (float*)d_ws;
    float* buf2 = buf1 + (size_t)65536 * 67;

    // level 3
    knn3_kernel<<<1024, 256, 0, stream>>>(x, pos, pos2, x_skip2, buf1);
    mlp2_kernel<384,128,128,16><<<4096/16, 128, 0, stream>>>(buf1, W3a, b3a, W3b, b3b, buf2, 4096);
    // level 2
    knn2_kernel<<<4096, 256, 0, stream>>>(buf2, pos2, pos1, x_skip1, buf1);
    mlp2_kernel<192,64,64,16><<<16384/16, 64, 0, stream>>>(buf1, W2a, b2a, W2b, b2b, buf2, 16384);
    // level 1
    knn1_kernel<<<16384, 256, 0, stream>>>(buf2, pos1, pos0, x_skip0, buf1);
    mlp_final_kernel<16><<<65536/16, 64, 0, stream>>>(buf1, W1a, b1a, W1b, b1b, W1c, b1c,
                                                      (float*)d_out, 65536);
}